// Round 12
// baseline (200.455 us; speedup 1.0000x reference)
//
#include <hip/hip_runtime.h>
#include <hip/hip_fp16.h>

// GCNConv + ReLU + global mean pool for MI355X (gfx950).
// Round 11b: same as round 11, compile fix only (trailing backslash in a //
// comment line-continued into the cnt8b declaration and deleted it).
// (1) pos[] eliminated — k_fill re-derives slots with a fresh replicated
// atomic (slot order within a bucket is irrelevant: commutative sum).
// (2) weighted degree fused into k_count; dinv folded into k_scan1.
// (3) scan3 replaced by 1-block scan2; consumers add bsum[k>>8] themselves.

#define REPS 8

typedef _Float16 f16;
typedef _Float16 half8 __attribute__((ext_vector_type(8)));
typedef float f32x4 __attribute__((ext_vector_type(4)));

// ---------- init: zero [cnt8|cnt8b|deg8f] (4.8MB, int4) + W -> Wt fp16 ----------
__global__ __launch_bounds__(256) void k_init(int* __restrict__ zbase, int Z4, int nzb,
                                              const float* __restrict__ W,
                                              f16* __restrict__ Wt) {
    int bid = blockIdx.x;
    int t = threadIdx.x;
    if (bid < nzb) {
        int i = bid * 256 + t;
        if (i < Z4) ((int4*)zbase)[i] = make_int4(0, 0, 0, 0);
    } else {
        int n = (bid - nzb) * 8 + (t >> 5);
        int k = (t & 31) * 4;
        union { f16 h[4]; uint2 u; } p;
#pragma unroll
        for (int j = 0; j < 4; ++j) p.h[j] = (f16)W[(k + j) * 128 + n];
        *(uint2*)&Wt[n * 128 + k] = p.u;
    }
}

// ---------- count + weighted degree (two 8-way-replicated atomics/edge) ----------
__global__ __launch_bounds__(256) void k_count(const int* __restrict__ ei,
                                               const float* __restrict__ ew,
                                               int* cnt8, float* deg8f, int E, int N) {
    int e = blockIdx.x * 256 + threadIdx.x;
    if (e >= E) return;
    int k = (e & (REPS - 1)) * N + ei[E + e];
    atomicAdd(&cnt8[k], 1);
    atomicAdd(&deg8f[k], ew[e]);
}

// ---------- scan1: chunk-local exclusive scan of counts (view k=node*8+rep),
//            chunk totals to bsum; first blocks also reduce deg8f -> dinv ----------
__global__ __launch_bounds__(256) void k_scan1(const int* __restrict__ cnt8,
                                               const float* __restrict__ deg8f,
                                               int* __restrict__ rp4,
                                               int* __restrict__ bsum,
                                               float* __restrict__ dinv,
                                               int M, int N) {
    __shared__ int wsum[4];
    int t = threadIdx.x;
    int k = blockIdx.x * 256 + t;
    int v = 0;
    if (k < M) v = cnt8[(k & (REPS - 1)) * N + (k >> 3)];
    int lane = t & 63, wid = t >> 6;
    int s = v;
#pragma unroll
    for (int o = 1; o < 64; o <<= 1) {
        int u = __shfl_up(s, o);
        if (lane >= o) s += u;
    }
    if (lane == 63) wsum[wid] = s;
    __syncthreads();
    int off = 0;
#pragma unroll
    for (int w = 0; w < 4; ++w)
        if (w < wid) off += wsum[w];
    if (k < M) rp4[k] = off + s - v;      // chunk-local exclusive
    if (t == 255) bsum[blockIdx.x] = off + s;

    // dinv duty: first ceil(N/256) blocks
    int n = blockIdx.x * 256 + t;
    if (n < N) {
        float d = 1.0f;                   // self-loop weight
#pragma unroll
        for (int r = 0; r < REPS; ++r) d += deg8f[r * N + n];
        dinv[n] = rsqrtf(d);
    }
}

// ---------- scan2: ONE block, exclusive scan of bsum[0..nb1) with carry ----------
__global__ __launch_bounds__(256) void k_scan2(int* __restrict__ bsum, int nb1) {
    __shared__ int wsum[4];
    __shared__ int sCarry;
    int t = threadIdx.x;
    int lane = t & 63, wid = t >> 6;
    if (t == 0) sCarry = 0;
    __syncthreads();
    for (int base = 0; base < nb1; base += 256) {
        int i = base + t;
        int v = (i < nb1) ? bsum[i] : 0;
        int s = v;
#pragma unroll
        for (int o = 1; o < 64; o <<= 1) {
            int u = __shfl_up(s, o);
            if (lane >= o) s += u;
        }
        if (lane == 63) wsum[wid] = s;
        __syncthreads();
        int off = 0;
#pragma unroll
        for (int w = 0; w < 4; ++w) if (w < wid) off += wsum[w];
        int tot = wsum[0] + wsum[1] + wsum[2] + wsum[3];
        int c = sCarry;
        __syncthreads();
        if (i < nb1) bsum[i] = c + off + s - v;   // exclusive
        if (t == 0) sCarry = c + tot;
        __syncthreads();
    }
}

// ---------- fill: fresh replicated atomic gives the slot; no pos array ----------
__global__ __launch_bounds__(256) void k_fill(const int* __restrict__ ei,
                                              const float* __restrict__ ew,
                                              const int* __restrict__ rp4,
                                              const int* __restrict__ bsum,
                                              int* cnt8b,
                                              int2* __restrict__ srcval, int E, int N) {
    int e = blockIdx.x * 256 + threadIdx.x;
    if (e >= E) return;
    int row = ei[e];
    int col = ei[E + e];
    int rep = e & (REPS - 1);
    int k = col * REPS + rep;
    int p = atomicAdd(&cnt8b[rep * N + col], 1);
    int slot = rp4[k] + bsum[k >> 8] + p;
    srcval[slot] = make_int2(row, __float_as_int(ew[e]));
}

// ---------- h' = dinv * (x @ W) -> fp16 via MFMA, 128x128 tile per block ----------
__global__ __launch_bounds__(256) void k_gemm(const float* __restrict__ x,
                                              const f16* __restrict__ Wt,
                                              const float* __restrict__ dinv,
                                              f16* __restrict__ hh, int N) {
    __shared__ f16 sX[128 * 136];   // pad 8 halves: 2-way (free) bank conflicts
    __shared__ f16 sW[128 * 136];
    int t = threadIdx.x;
    int row0 = blockIdx.x * 128;
#pragma unroll
    for (int it = 0; it < 8; ++it) {
        int i = t + 256 * it;
        int n = i >> 4, k8 = (i & 15) * 8;
        *(half8*)&sW[n * 136 + k8] = *(const half8*)&Wt[n * 128 + k8];
    }
#pragma unroll
    for (int it = 0; it < 16; ++it) {
        int i = t + 256 * it;
        int r = i >> 5, c4 = (i & 31) * 4;
        float4 xv = make_float4(0.f, 0.f, 0.f, 0.f);
        if (row0 + r < N) xv = *(const float4*)&x[(size_t)(row0 + r) * 128 + c4];
        union { f16 h[4]; uint2 u; } p;
        p.h[0] = (f16)xv.x; p.h[1] = (f16)xv.y; p.h[2] = (f16)xv.z; p.h[3] = (f16)xv.w;
        *(uint2*)&sX[r * 136 + c4] = p.u;
    }
    __syncthreads();

    int w = t >> 6, l = t & 63;
    int lm = l & 15, lg = l >> 4;
    f32x4 acc[2][8];
#pragma unroll
    for (int rt = 0; rt < 2; ++rt)
#pragma unroll
        for (int ct = 0; ct < 8; ++ct) acc[rt][ct] = (f32x4){0.f, 0.f, 0.f, 0.f};

    int arow = w * 32 + lm;
#pragma unroll
    for (int ks = 0; ks < 4; ++ks) {
        int ko = ks * 32 + lg * 8;        // K-bijection identical for A and B
        half8 a0 = *(const half8*)&sX[arow * 136 + ko];
        half8 a1 = *(const half8*)&sX[(arow + 16) * 136 + ko];
#pragma unroll
        for (int ct = 0; ct < 8; ++ct) {
            half8 bf = *(const half8*)&sW[(ct * 16 + lm) * 136 + ko];
            acc[0][ct] = __builtin_amdgcn_mfma_f32_16x16x32_f16(a0, bf, acc[0][ct], 0, 0, 0);
            acc[1][ct] = __builtin_amdgcn_mfma_f32_16x16x32_f16(a1, bf, acc[1][ct], 0, 0, 0);
        }
    }

    // epilogue: scale by dinv, repack through this wave's own sX rows
#pragma unroll
    for (int rt = 0; rt < 2; ++rt) {
#pragma unroll
        for (int r = 0; r < 4; ++r) {
            int lrow = w * 32 + rt * 16 + lg * 4 + r;   // D row = (lane>>4)*4 + reg
            int grow = row0 + lrow;
            float di = (grow < N) ? dinv[grow] : 0.f;
#pragma unroll
            for (int ct = 0; ct < 8; ++ct)
                sX[lrow * 136 + ct * 16 + lm] = (f16)(acc[rt][ct][r] * di);  // D col = lane&15
        }
    }
#pragma unroll
    for (int it = 0; it < 8; ++it) {
        int i = l + 64 * it;
        int lr = i >> 4, k8 = (i & 15) * 8;
        int grow = row0 + w * 32 + lr;
        if (grow < N)
            *(half8*)&hh[(size_t)grow * 128 + k8] =
                *(const half8*)&sX[(w * 32 + lr) * 136 + k8];
    }
}

// ---------- gather-aggregate: quarter-wave, 4 edges/step, 2-step unroll ----------
// out[i] = relu( dinv_i * ( sum_j w_j*h'[src_j] + h'_i ) + b ),  h' = dinv*h
__global__ __launch_bounds__(256) void k_aggregate(const int2* __restrict__ srcval,
                                                   const int* __restrict__ rp4,
                                                   const int* __restrict__ bsum,
                                                   const f16* __restrict__ hh,
                                                   const float* __restrict__ dinv,
                                                   const float* __restrict__ b,
                                                   float* __restrict__ out, int N, int M, int E) {
    int node = blockIdx.x * 4 + (threadIdx.x >> 6);
    if (node >= N) return;
    int lane = threadIdx.x & 63;
    int g = lane >> 4;                    // edge group 0..3
    int lm = lane & 15;
    int d0 = lm * 8;                      // this lane's 8 dims
    int bk = node * REPS;
    int ek = bk + REPS;
    int beg = rp4[bk] + bsum[bk >> 8];
    int end = (ek == M) ? E : rp4[ek] + bsum[ek >> 8];

    float acc0[8], acc1[8];
#pragma unroll
    for (int k = 0; k < 8; ++k) { acc0[k] = 0.f; acc1[k] = 0.f; }

    int j = beg;
    for (; j + 8 <= end; j += 8) {
        int2 ma = srcval[j + g];
        int2 mb = srcval[j + 4 + g];
        half8 va = *(const half8*)&hh[(size_t)ma.x * 128 + d0];
        half8 vb = *(const half8*)&hh[(size_t)mb.x * 128 + d0];
        float wa = __int_as_float(ma.y);
        float wb = __int_as_float(mb.y);
#pragma unroll
        for (int k = 0; k < 8; ++k) {
            acc0[k] = fmaf((float)va[k], wa, acc0[k]);
            acc1[k] = fmaf((float)vb[k], wb, acc1[k]);
        }
    }
    if (j + 4 <= end) {
        int2 ma = srcval[j + g];
        half8 va = *(const half8*)&hh[(size_t)ma.x * 128 + d0];
        float wa = __int_as_float(ma.y);
#pragma unroll
        for (int k = 0; k < 8; ++k) acc0[k] = fmaf((float)va[k], wa, acc0[k]);
        j += 4;
    }
    int r = end - j;                      // 0..3 leftover edges
    if (r > 0) {
        int2 ma = srcval[j + min(g, r - 1)];
        float wa = (g < r) ? __int_as_float(ma.y) : 0.f;
        half8 va = *(const half8*)&hh[(size_t)ma.x * 128 + d0];
#pragma unroll
        for (int k = 0; k < 8; ++k) acc0[k] = fmaf((float)va[k], wa, acc0[k]);
    }

#pragma unroll
    for (int k = 0; k < 8; ++k) acc0[k] += acc1[k];
#pragma unroll
    for (int k = 0; k < 8; ++k) acc0[k] += __shfl_xor(acc0[k], 16);
#pragma unroll
    for (int k = 0; k < 8; ++k) acc0[k] += __shfl_xor(acc0[k], 32);

    if (g == 0) {                         // lanes 0..15 finish + store 512B row
        float di = dinv[node];
        half8 hs = *(const half8*)&hh[(size_t)node * 128 + d0];
        float4 bv0 = *(const float4*)&b[d0];
        float4 bv1 = *(const float4*)&b[d0 + 4];
        float4 o0, o1;
        o0.x = fmaxf(fmaf(acc0[0] + (float)hs[0], di, bv0.x), 0.f);
        o0.y = fmaxf(fmaf(acc0[1] + (float)hs[1], di, bv0.y), 0.f);
        o0.z = fmaxf(fmaf(acc0[2] + (float)hs[2], di, bv0.z), 0.f);
        o0.w = fmaxf(fmaf(acc0[3] + (float)hs[3], di, bv0.w), 0.f);
        o1.x = fmaxf(fmaf(acc0[4] + (float)hs[4], di, bv1.x), 0.f);
        o1.y = fmaxf(fmaf(acc0[5] + (float)hs[5], di, bv1.y), 0.f);
        o1.z = fmaxf(fmaf(acc0[6] + (float)hs[6], di, bv1.z), 0.f);
        o1.w = fmaxf(fmaf(acc0[7] + (float)hs[7], di, bv1.w), 0.f);
        *(float4*)&out[(size_t)node * 128 + d0] = o0;
        *(float4*)&out[(size_t)node * 128 + d0 + 4] = o1;
    }
}

// ---------- pool: one block per graph, bounds by binary search, no atomics ----------
__global__ __launch_bounds__(256) void k_pool(const float* __restrict__ out,
                                              const int* __restrict__ batch,
                                              float* __restrict__ pool, int N, int G) {
    __shared__ float sacc[256];
    __shared__ int bounds[2];
    int g = blockIdx.x;
    int t = threadIdx.x;
    if (t < 2) {
        int target = g + t;
        int lo = 0, hi = N;
        while (lo < hi) {
            int mid = (lo + hi) >> 1;
            if (batch[mid] < target) lo = mid + 1; else hi = mid;
        }
        bounds[t] = lo;
    }
    __syncthreads();
    int lo = bounds[0], hi = bounds[1];
    int d = t & 127, r = t >> 7;
    float s = 0.f;
    for (int n = lo + r; n < hi; n += 2)
        s += out[(size_t)n * 128 + d];
    sacc[t] = s;
    __syncthreads();
    if (t < 128) {
        float tot = sacc[t] + sacc[t + 128];
        pool[(size_t)g * 128 + t] = tot / fmaxf((float)(hi - lo), 1.0f);
    }
}

extern "C" void kernel_launch(void* const* d_in, const int* in_sizes, int n_in,
                              void* d_out, int out_size, void* d_ws, size_t ws_size,
                              hipStream_t stream) {
    const float* x     = (const float*)d_in[0];
    const int*   ei    = (const int*)d_in[1];
    const float* ew    = (const float*)d_in[2];
    const int*   batch = (const int*)d_in[3];
    const float* W     = (const float*)d_in[4];
    const float* b     = (const float*)d_in[5];

    int N = in_sizes[3];                  // 50000
    int E = in_sizes[2];                  // 800000
    int G = (out_size - N * 128) / 128;   // 500
    int M = N * REPS;
    int nb1 = (M + 255) / 256;

    float* out  = (float*)d_out;
    float* pool = out + (size_t)N * 128;

    // workspace layout (~26 MB); cnt8, cnt8b, deg8f form one contiguous zero region
    f16*    hh     = (f16*)d_ws;                        // N*128 f16 (12.8 MB)
    int2*   srcval = (int2*)(hh + (size_t)N * 128);     // E int2 (6.4 MB)
    float*  dinv   = (float*)(srcval + E);              // N f
    int*    cnt8   = (int*)(dinv + N);                  // 8N i (zero region start)
    int*    cnt8b  = cnt8 + M;                          // 8N i
    float*  deg8f  = (float*)(cnt8b + M);               // 8N f (zero region end)
    int*    rp4    = (int*)(deg8f + M);                 // 8N i
    int*    bsum   = rp4 + M;                           // nb1 i
    f16*    Wt     = (f16*)(((uintptr_t)(bsum + nb1) + 15) & ~(uintptr_t)15);  // 32 KB

    int Z4  = (3 * M) / 4;                 // int4 chunks to zero (cnt8|cnt8b|deg8f)
    int nzb = (Z4 + 255) / 256;
    k_init<<<nzb + 16, 256, 0, stream>>>(cnt8, Z4, nzb, W, Wt);
    k_count<<<(E + 255) / 256, 256, 0, stream>>>(ei, ew, cnt8, deg8f, E, N);
    k_scan1<<<nb1, 256, 0, stream>>>(cnt8, deg8f, rp4, bsum, dinv, M, N);
    k_scan2<<<1, 256, 0, stream>>>(bsum, nb1);
    k_fill<<<(E + 255) / 256, 256, 0, stream>>>(ei, ew, rp4, bsum, cnt8b, srcval, E, N);
    k_gemm<<<(N + 127) / 128, 256, 0, stream>>>(x, Wt, dinv, hh, N);
    k_aggregate<<<(N + 3) / 4, 256, 0, stream>>>(srcval, rp4, bsum, hh, dinv, b, out, N, M, E);
    k_pool<<<G, 256, 0, stream>>>(out, batch, pool, N, G);
}

// Round 13
// 140.719 us; speedup vs baseline: 1.4245x; 1.4245x over previous
//
#include <hip/hip_runtime.h>
#include <hip/hip_fp16.h>

// GCNConv + ReLU + global mean pool for MI355X (gfx950).
// Round 13: revert round-11's extra scattered-atomic passes (measured: scattered
// 4B atomics run at ~22 G/s flat; each extra pass = +36us). Round-10 structure +
// (a) XCD-local atomic replicas: rep = blockIdx.x & 7 -> replica slab touched by
// one XCD's L2 only (correct under ANY block->XCD mapping; fill re-derives rep
// from e>>8); (b) u64 packed atomic: count in bits 40+, fixed-point sum(w) in
// low 40 bits (2^-20 quantization, error ~1e-6) -> k_deg_csr eliminated, dinv
// computed in k_scan1. scan3 stays eliminated (consumers add bsum[k>>8]).

#define REPS 8
#define WSCALE 1048576.0f          // 2^20 fixed-point for edge weights
#define WMASK ((1ull << 40) - 1)

typedef _Float16 f16;
typedef _Float16 half8 __attribute__((ext_vector_type(8)));
typedef float f32x4 __attribute__((ext_vector_type(4)));

// ---------- init: zero cnt64 (3.2MB, int4) + W -> Wt fp16 [n][k] ----------
__global__ __launch_bounds__(256) void k_init(int* __restrict__ zbase, int Z4, int nzb,
                                              const float* __restrict__ W,
                                              f16* __restrict__ Wt) {
    int bid = blockIdx.x;
    int t = threadIdx.x;
    if (bid < nzb) {
        int i = bid * 256 + t;
        if (i < Z4) ((int4*)zbase)[i] = make_int4(0, 0, 0, 0);
    } else {
        int n = (bid - nzb) * 8 + (t >> 5);
        int k = (t & 31) * 4;
        union { f16 h[4]; uint2 u; } p;
#pragma unroll
        for (int j = 0; j < 4; ++j) p.h[j] = (f16)W[(k + j) * 128 + n];
        *(uint2*)&Wt[n * 128 + k] = p.u;
    }
}

// ---------- count+degree: ONE u64 atomic/edge into the block's XCD-local replica;
//            returned old value gives the insertion position ----------
__global__ __launch_bounds__(256) void k_count64(const int* __restrict__ ei,
                                                 const float* __restrict__ ew,
                                                 unsigned long long* cnt64,
                                                 int* __restrict__ pos, int E, int N) {
    int e = blockIdx.x * 256 + threadIdx.x;
    if (e >= E) return;
    int col = ei[E + e];
    int rep = blockIdx.x & (REPS - 1);    // XCD-local under round-robin dispatch
    unsigned long long add =
        (1ull << 40) | (unsigned long long)(ew[e] * WSCALE + 0.5f);
    unsigned long long old = atomicAdd(&cnt64[(size_t)rep * N + col], add);
    pos[e] = (int)(old >> 40);
}

// ---------- scan1: chunk-local exclusive scan of counts (view k = node*8+rep),
//            chunk totals -> bsum; first ceil(N/256) blocks also emit dinv ----------
__global__ __launch_bounds__(256) void k_scan1(const unsigned long long* __restrict__ cnt64,
                                               int* __restrict__ rp4,
                                               int* __restrict__ bsum,
                                               float* __restrict__ dinv,
                                               int M, int N) {
    __shared__ int wsum[4];
    int t = threadIdx.x;
    int k = blockIdx.x * 256 + t;
    int v = 0;
    if (k < M) v = (int)(cnt64[(size_t)(k & (REPS - 1)) * N + (k >> 3)] >> 40);
    int lane = t & 63, wid = t >> 6;
    int s = v;
#pragma unroll
    for (int o = 1; o < 64; o <<= 1) {
        int u = __shfl_up(s, o);
        if (lane >= o) s += u;
    }
    if (lane == 63) wsum[wid] = s;
    __syncthreads();
    int off = 0;
#pragma unroll
    for (int w = 0; w < 4; ++w)
        if (w < wid) off += wsum[w];
    if (k < M) rp4[k] = off + s - v;      // chunk-local exclusive
    if (t == 255) bsum[blockIdx.x] = off + s;

    // dinv duty: first ceil(N/256) blocks
    int n = blockIdx.x * 256 + t;
    if (n < N) {
        unsigned long long wsumq = 0;
#pragma unroll
        for (int r = 0; r < REPS; ++r) wsumq += cnt64[(size_t)r * N + n] & WMASK;
        float d = 1.0f + (float)wsumq * (1.0f / WSCALE);   // self-loop + sum(w)
        dinv[n] = rsqrtf(d);
    }
}

// ---------- scan2: ONE block, exclusive scan of bsum[0..nb1) with carry ----------
__global__ __launch_bounds__(256) void k_scan2(int* __restrict__ bsum, int nb1) {
    __shared__ int wsum[4];
    __shared__ int sCarry;
    int t = threadIdx.x;
    int lane = t & 63, wid = t >> 6;
    if (t == 0) sCarry = 0;
    __syncthreads();
    for (int base = 0; base < nb1; base += 256) {
        int i = base + t;
        int v = (i < nb1) ? bsum[i] : 0;
        int s = v;
#pragma unroll
        for (int o = 1; o < 64; o <<= 1) {
            int u = __shfl_up(s, o);
            if (lane >= o) s += u;
        }
        if (lane == 63) wsum[wid] = s;
        __syncthreads();
        int off = 0;
#pragma unroll
        for (int w = 0; w < 4; ++w) if (w < wid) off += wsum[w];
        int tot = wsum[0] + wsum[1] + wsum[2] + wsum[3];
        int c = sCarry;
        __syncthreads();
        if (i < nb1) bsum[i] = c + off + s - v;   // exclusive
        if (t == 0) sCarry = c + tot;
        __syncthreads();
    }
}

// ---------- fill: atomic-free, slot from rp4 + bsum + coalesced pos[] ----------
__global__ __launch_bounds__(256) void k_fill(const int* __restrict__ ei,
                                              const float* __restrict__ ew,
                                              const int* __restrict__ rp4,
                                              const int* __restrict__ bsum,
                                              const int* __restrict__ pos,
                                              int2* __restrict__ srcval, int E) {
    int e = blockIdx.x * 256 + threadIdx.x;
    if (e >= E) return;
    int row = ei[e];
    int col = ei[E + e];
    int rep = blockIdx.x & (REPS - 1);    // must match k_count64's rep formula
    int k = col * REPS + rep;
    int slot = rp4[k] + bsum[k >> 8] + pos[e];
    srcval[slot] = make_int2(row, __float_as_int(ew[e]));
}

// ---------- h' = dinv * (x @ W) -> fp16 via MFMA, 128x128 tile per block ----------
__global__ __launch_bounds__(256) void k_gemm(const float* __restrict__ x,
                                              const f16* __restrict__ Wt,
                                              const float* __restrict__ dinv,
                                              f16* __restrict__ hh, int N) {
    __shared__ f16 sX[128 * 136];   // pad 8 halves: 2-way (free) bank conflicts
    __shared__ f16 sW[128 * 136];
    int t = threadIdx.x;
    int row0 = blockIdx.x * 128;
#pragma unroll
    for (int it = 0; it < 8; ++it) {
        int i = t + 256 * it;
        int n = i >> 4, k8 = (i & 15) * 8;
        *(half8*)&sW[n * 136 + k8] = *(const half8*)&Wt[n * 128 + k8];
    }
#pragma unroll
    for (int it = 0; it < 16; ++it) {
        int i = t + 256 * it;
        int r = i >> 5, c4 = (i & 31) * 4;
        float4 xv = make_float4(0.f, 0.f, 0.f, 0.f);
        if (row0 + r < N) xv = *(const float4*)&x[(size_t)(row0 + r) * 128 + c4];
        union { f16 h[4]; uint2 u; } p;
        p.h[0] = (f16)xv.x; p.h[1] = (f16)xv.y; p.h[2] = (f16)xv.z; p.h[3] = (f16)xv.w;
        *(uint2*)&sX[r * 136 + c4] = p.u;
    }
    __syncthreads();

    int w = t >> 6, l = t & 63;
    int lm = l & 15, lg = l >> 4;
    f32x4 acc[2][8];
#pragma unroll
    for (int rt = 0; rt < 2; ++rt)
#pragma unroll
        for (int ct = 0; ct < 8; ++ct) acc[rt][ct] = (f32x4){0.f, 0.f, 0.f, 0.f};

    int arow = w * 32 + lm;
#pragma unroll
    for (int ks = 0; ks < 4; ++ks) {
        int ko = ks * 32 + lg * 8;        // K-bijection identical for A and B
        half8 a0 = *(const half8*)&sX[arow * 136 + ko];
        half8 a1 = *(const half8*)&sX[(arow + 16) * 136 + ko];
#pragma unroll
        for (int ct = 0; ct < 8; ++ct) {
            half8 bf = *(const half8*)&sW[(ct * 16 + lm) * 136 + ko];
            acc[0][ct] = __builtin_amdgcn_mfma_f32_16x16x32_f16(a0, bf, acc[0][ct], 0, 0, 0);
            acc[1][ct] = __builtin_amdgcn_mfma_f32_16x16x32_f16(a1, bf, acc[1][ct], 0, 0, 0);
        }
    }

    // epilogue: scale by dinv, repack through this wave's own sX rows
#pragma unroll
    for (int rt = 0; rt < 2; ++rt) {
#pragma unroll
        for (int r = 0; r < 4; ++r) {
            int lrow = w * 32 + rt * 16 + lg * 4 + r;   // D row = (lane>>4)*4 + reg
            int grow = row0 + lrow;
            float di = (grow < N) ? dinv[grow] : 0.f;
#pragma unroll
            for (int ct = 0; ct < 8; ++ct)
                sX[lrow * 136 + ct * 16 + lm] = (f16)(acc[rt][ct][r] * di);  // D col = lane&15
        }
    }
#pragma unroll
    for (int it = 0; it < 8; ++it) {
        int i = l + 64 * it;
        int lr = i >> 4, k8 = (i & 15) * 8;
        int grow = row0 + w * 32 + lr;
        if (grow < N)
            *(half8*)&hh[(size_t)grow * 128 + k8] =
                *(const half8*)&sX[(w * 32 + lr) * 136 + k8];
    }
}

// ---------- gather-aggregate: quarter-wave, 4 edges/step, 2-step unroll ----------
// out[i] = relu( dinv_i * ( sum_j w_j*h'[src_j] + h'_i ) + b ),  h' = dinv*h
__global__ __launch_bounds__(256) void k_aggregate(const int2* __restrict__ srcval,
                                                   const int* __restrict__ rp4,
                                                   const int* __restrict__ bsum,
                                                   const f16* __restrict__ hh,
                                                   const float* __restrict__ dinv,
                                                   const float* __restrict__ b,
                                                   float* __restrict__ out, int N, int M, int E) {
    int node = blockIdx.x * 4 + (threadIdx.x >> 6);
    if (node >= N) return;
    int lane = threadIdx.x & 63;
    int g = lane >> 4;                    // edge group 0..3
    int lm = lane & 15;
    int d0 = lm * 8;                      // this lane's 8 dims
    int bk = node * REPS;
    int ek = bk + REPS;
    int beg = rp4[bk] + bsum[bk >> 8];
    int end = (ek == M) ? E : rp4[ek] + bsum[ek >> 8];

    float acc0[8], acc1[8];
#pragma unroll
    for (int k = 0; k < 8; ++k) { acc0[k] = 0.f; acc1[k] = 0.f; }

    int j = beg;
    for (; j + 8 <= end; j += 8) {
        int2 ma = srcval[j + g];
        int2 mb = srcval[j + 4 + g];
        half8 va = *(const half8*)&hh[(size_t)ma.x * 128 + d0];
        half8 vb = *(const half8*)&hh[(size_t)mb.x * 128 + d0];
        float wa = __int_as_float(ma.y);
        float wb = __int_as_float(mb.y);
#pragma unroll
        for (int k = 0; k < 8; ++k) {
            acc0[k] = fmaf((float)va[k], wa, acc0[k]);
            acc1[k] = fmaf((float)vb[k], wb, acc1[k]);
        }
    }
    if (j + 4 <= end) {
        int2 ma = srcval[j + g];
        half8 va = *(const half8*)&hh[(size_t)ma.x * 128 + d0];
        float wa = __int_as_float(ma.y);
#pragma unroll
        for (int k = 0; k < 8; ++k) acc0[k] = fmaf((float)va[k], wa, acc0[k]);
        j += 4;
    }
    int r = end - j;                      // 0..3 leftover edges
    if (r > 0) {
        int2 ma = srcval[j + min(g, r - 1)];
        float wa = (g < r) ? __int_as_float(ma.y) : 0.f;
        half8 va = *(const half8*)&hh[(size_t)ma.x * 128 + d0];
#pragma unroll
        for (int k = 0; k < 8; ++k) acc0[k] = fmaf((float)va[k], wa, acc0[k]);
    }

#pragma unroll
    for (int k = 0; k < 8; ++k) acc0[k] += acc1[k];
#pragma unroll
    for (int k = 0; k < 8; ++k) acc0[k] += __shfl_xor(acc0[k], 16);
#pragma unroll
    for (int k = 0; k < 8; ++k) acc0[k] += __shfl_xor(acc0[k], 32);

    if (g == 0) {                         // lanes 0..15 finish + store 512B row
        float di = dinv[node];
        half8 hs = *(const half8*)&hh[(size_t)node * 128 + d0];
        float4 bv0 = *(const float4*)&b[d0];
        float4 bv1 = *(const float4*)&b[d0 + 4];
        float4 o0, o1;
        o0.x = fmaxf(fmaf(acc0[0] + (float)hs[0], di, bv0.x), 0.f);
        o0.y = fmaxf(fmaf(acc0[1] + (float)hs[1], di, bv0.y), 0.f);
        o0.z = fmaxf(fmaf(acc0[2] + (float)hs[2], di, bv0.z), 0.f);
        o0.w = fmaxf(fmaf(acc0[3] + (float)hs[3], di, bv0.w), 0.f);
        o1.x = fmaxf(fmaf(acc0[4] + (float)hs[4], di, bv1.x), 0.f);
        o1.y = fmaxf(fmaf(acc0[5] + (float)hs[5], di, bv1.y), 0.f);
        o1.z = fmaxf(fmaf(acc0[6] + (float)hs[6], di, bv1.z), 0.f);
        o1.w = fmaxf(fmaf(acc0[7] + (float)hs[7], di, bv1.w), 0.f);
        *(float4*)&out[(size_t)node * 128 + d0] = o0;
        *(float4*)&out[(size_t)node * 128 + d0 + 4] = o1;
    }
}

// ---------- pool: one block per graph, bounds by binary search, no atomics ----------
__global__ __launch_bounds__(256) void k_pool(const float* __restrict__ out,
                                              const int* __restrict__ batch,
                                              float* __restrict__ pool, int N, int G) {
    __shared__ float sacc[256];
    __shared__ int bounds[2];
    int g = blockIdx.x;
    int t = threadIdx.x;
    if (t < 2) {
        int target = g + t;
        int lo = 0, hi = N;
        while (lo < hi) {
            int mid = (lo + hi) >> 1;
            if (batch[mid] < target) lo = mid + 1; else hi = mid;
        }
        bounds[t] = lo;
    }
    __syncthreads();
    int lo = bounds[0], hi = bounds[1];
    int d = t & 127, r = t >> 7;
    float s = 0.f;
    for (int n = lo + r; n < hi; n += 2)
        s += out[(size_t)n * 128 + d];
    sacc[t] = s;
    __syncthreads();
    if (t < 128) {
        float tot = sacc[t] + sacc[t + 128];
        pool[(size_t)g * 128 + t] = tot / fmaxf((float)(hi - lo), 1.0f);
    }
}

extern "C" void kernel_launch(void* const* d_in, const int* in_sizes, int n_in,
                              void* d_out, int out_size, void* d_ws, size_t ws_size,
                              hipStream_t stream) {
    const float* x     = (const float*)d_in[0];
    const int*   ei    = (const int*)d_in[1];
    const float* ew    = (const float*)d_in[2];
    const int*   batch = (const int*)d_in[3];
    const float* W     = (const float*)d_in[4];
    const float* b     = (const float*)d_in[5];

    int N = in_sizes[3];                  // 50000
    int E = in_sizes[2];                  // 800000
    int G = (out_size - N * 128) / 128;   // 500
    int M = N * REPS;
    int nb1 = (M + 255) / 256;

    float* out  = (float*)d_out;
    float* pool = out + (size_t)N * 128;

    // workspace layout (~27.5 MB)
    f16*    hh     = (f16*)d_ws;                            // N*128 f16 (12.8 MB)
    int2*   srcval = (int2*)(hh + (size_t)N * 128);         // E int2 (6.4 MB)
    float*  dinv   = (float*)(srcval + E);                  // N f (0.2 MB)
    unsigned long long* cnt64 =
        (unsigned long long*)(dinv + N);                    // 8N u64 (3.2 MB)
    int*    rp4    = (int*)(cnt64 + M);                     // 8N i (1.6 MB)
    int*    bsum   = rp4 + M;                               // nb1 i
    int*    pos    = bsum + nb1;                            // E i (3.2 MB)
    f16*    Wt     = (f16*)(((uintptr_t)(pos + E) + 15) & ~(uintptr_t)15);  // 32 KB

    int Z4  = M / 2;                       // int4 chunks to zero (8N u64 = M*8 B)
    int nzb = (Z4 + 255) / 256;
    k_init<<<nzb + 16, 256, 0, stream>>>((int*)cnt64, Z4, nzb, W, Wt);
    k_count64<<<(E + 255) / 256, 256, 0, stream>>>(ei, ew, cnt64, pos, E, N);
    k_scan1<<<nb1, 256, 0, stream>>>(cnt64, rp4, bsum, dinv, M, N);
    k_scan2<<<1, 256, 0, stream>>>(bsum, nb1);
    k_fill<<<(E + 255) / 256, 256, 0, stream>>>(ei, ew, rp4, bsum, pos, srcval, E);
    k_gemm<<<(N + 127) / 128, 256, 0, stream>>>(x, Wt, dinv, hh, N);
    k_aggregate<<<(N + 3) / 4, 256, 0, stream>>>(srcval, rp4, bsum, hh, dinv, b, out, N, M, E);
    k_pool<<<G, 256, 0, stream>>>(out, batch, pool, N, G);
}